// Round 6
// baseline (762.904 us; speedup 1.0000x reference)
//
#include <hip/hip_runtime.h>
#include <hip/hip_bf16.h>
#include <hip/hip_cooperative_groups.h>

namespace cg = cooperative_groups;

// GCN layer: out = D^-1/2 (A + I) D^-1/2 (x W^T + b)
// R11: 3 dispatches total.
//   1. k_sort (cooperative, 782 blocks): hist -> grid.sync -> scan ->
//      grid.sync -> place -> grid.sync -> sortB (833 units looped).
//      Phase bodies verbatim from R10's proven kernels; ftail zeroed in
//      phase 1 (memset launch deleted).
//   2. k_gemm: hs = bf16( rinv[r] * (x W^T + b) ) via mfma_f32_16x16x32_bf16.
//      In-degrees derived per block from its 2 E2 buckets (LDS hist aliased
//      into wh, consumed into registers before W staging) — k_deg deleted.
//   3. k_spmm: per fine bucket: LDS counting sort -> exact per-node runs,
//      16-lane uint4 gather 8-deep; rinv computed locally from bins.

#define N_NODES 100000
#define N_EDGES 1600000
#define CH 128
#define NC 49            // coarse buckets of 2048 nodes
#define NBLKA 782        // sort blocks (2048 edges each)
#define CAPC 34816       // 17*2048; mean 32768 + 11 sigma
#define NCHUNK 17
#define NFB 1563         // fine buckets of 64 nodes (1563*64 = 100032)
#define FCAP 1280        // mean 1024 + 8 sigma

using bf16x8 = __attribute__((ext_vector_type(8))) short;   // 8 bf16 in 4 VGPRs
using f32x4  = __attribute__((ext_vector_type(4))) float;   // MFMA acc

__device__ inline unsigned short f2bf(float f) {          // RNE float->bf16
    unsigned u = __float_as_uint(f);
    u += 0x7fffu + ((u >> 16) & 1u);
    return (unsigned short)(u >> 16);
}
__device__ inline float bflo(unsigned u) { return __uint_as_float(u << 16); }
__device__ inline float bfhi(unsigned u) { return __uint_as_float(u & 0xffff0000u); }

// ---------------- fused sort: hist -> scan -> place -> sortB ----------------
__global__ __launch_bounds__(256) void k_sort(const int* __restrict__ src,
                                              const int* __restrict__ dst,
                                              int* __restrict__ ctail,
                                              int* __restrict__ ftail,
                                              int* __restrict__ histG,
                                              unsigned* __restrict__ E1,
                                              unsigned* __restrict__ E2) {
    __shared__ int hist[NC];
    __shared__ int boff[NC + 1];
    __shared__ int cur[NC];
    __shared__ int gb[NC];
    __shared__ int part[256];
    __shared__ unsigned stage[2048];
    cg::grid_group gg = cg::this_grid();

    const int t    = threadIdx.x;
    const int bid  = blockIdx.x;
    const int base = bid * 2048;
    const int n    = min(2048, N_EDGES - base);   // 2048, or 512 in last block

    // ---- phase 1: per-block 49-bin histogram (+ ftail zero) ----
    { int i = bid * 256 + t; if (i < 1600) ftail[i] = 0; }
    if (t < NC) hist[t] = 0;
    __syncthreads();
#pragma unroll
    for (int h = 0; h < 2; ++h) {
        int idx = h * 1024 + 4 * t;
        if (idx < n) {
            int4 dv = *(const int4*)&dst[base + idx];
            atomicAdd(&hist[dv.x >> 11], 1);
            atomicAdd(&hist[dv.y >> 11], 1);
            atomicAdd(&hist[dv.z >> 11], 1);
            atomicAdd(&hist[dv.w >> 11], 1);
        }
    }
    __syncthreads();
    if (t < NC) histG[(size_t)t * NBLKA + bid] = hist[t];

    __threadfence();
    gg.sync();
    __threadfence();

    // ---- phase 2: exclusive scan per bucket (blocks 0..48) ----
    if (bid < NC) {
        int* h = histG + (size_t)bid * NBLKA;
        const int cb4 = t * 4;                   // 256*4 >= 782
        int a0 = 0, a1 = 0, a2 = 0, a3 = 0;
        if (cb4 + 0 < NBLKA) a0 = h[cb4 + 0];
        if (cb4 + 1 < NBLKA) a1 = h[cb4 + 1];
        if (cb4 + 2 < NBLKA) a2 = h[cb4 + 2];
        if (cb4 + 3 < NBLKA) a3 = h[cb4 + 3];
        const int s = a0 + a1 + a2 + a3;
        part[t] = s;
        __syncthreads();
        for (int off = 1; off < 256; off <<= 1) {    // Hillis-Steele inclusive
            int x = (t >= off) ? part[t - off] : 0;
            __syncthreads();
            part[t] += x;
            __syncthreads();
        }
        int r = part[t] - s;                         // exclusive prefix
        if (t == 255) ctail[bid] = part[255];
        if (cb4 + 0 < NBLKA) { h[cb4 + 0] = r; r += a0; }
        if (cb4 + 1 < NBLKA) { h[cb4 + 1] = r; r += a1; }
        if (cb4 + 2 < NBLKA) { h[cb4 + 2] = r; r += a2; }
        if (cb4 + 3 < NBLKA) { h[cb4 + 3] = r; r += a3; }
    }

    __threadfence();
    gg.sync();
    __threadfence();

    // ---- phase 3: LDS counting sort, writeout at exact offsets ----
    {
        if (t < NC) {
            hist[t] = 0;
            gb[t] = histG[(size_t)t * NBLKA + bid];  // exact, no atomics
        }
        __syncthreads();

        int s[8], d[8];
#pragma unroll
        for (int h = 0; h < 2; ++h) {
            int idx = h * 1024 + 4 * t;
            if (idx < n) {               // n in {512,2048}: int4 never straddles
                int4 sv = *(const int4*)&src[base + idx];
                int4 dv = *(const int4*)&dst[base + idx];
                s[4*h+0] = sv.x; s[4*h+1] = sv.y; s[4*h+2] = sv.z; s[4*h+3] = sv.w;
                d[4*h+0] = dv.x; d[4*h+1] = dv.y; d[4*h+2] = dv.z; d[4*h+3] = dv.w;
            } else {
                d[4*h+0] = d[4*h+1] = d[4*h+2] = d[4*h+3] = -1;
                s[4*h+0] = s[4*h+1] = s[4*h+2] = s[4*h+3] = 0;
            }
        }
#pragma unroll
        for (int j = 0; j < 8; ++j)
            if (d[j] >= 0) atomicAdd(&hist[d[j] >> 11], 1);
        __syncthreads();

        if (t == 0) {
            int run = 0;
            for (int k = 0; k < NC; ++k) { boff[k] = run; run += hist[k]; }
            boff[NC] = run;
        }
        __syncthreads();
        if (t < NC) cur[t] = boff[t];
        __syncthreads();

#pragma unroll
        for (int j = 0; j < 8; ++j)
            if (d[j] >= 0) {
                int k = d[j] >> 11;
                int pos = atomicAdd(&cur[k], 1);
                stage[pos] = ((unsigned)s[j] << 11) | (unsigned)(d[j] & 2047);
            }
        __syncthreads();

        const int tot = boff[NC];
        for (int i = t; i < tot; i += 256) {
            int lo = 0, hi = NC;          // invariant: boff[lo] <= i < boff[hi]
#pragma unroll
            for (int it = 0; it < 6; ++it) {
                int mid = (lo + hi) >> 1;
                bool c = (boff[mid] <= i);
                lo = c ? mid : lo;
                hi = c ? hi : mid;
            }
            int p = gb[lo] + (i - boff[lo]);
            if (p < CAPC) E1[(size_t)lo * CAPC + p] = stage[i];
        }
    }

    __threadfence();
    gg.sync();
    __threadfence();

    // ---- phase 4: re-bin coarse -> 64-node fine buckets (<=2 units/block) ----
    for (int u = bid; u < NC * NCHUNK; u += NBLKA) {
        const int cb = u / NCHUNK;
        const int ch = u % NCHUNK;
        int cnt = ctail[cb]; if (cnt > CAPC) cnt = CAPC;
        const int begin = ch * 2048;
        int nn = cnt - begin;
        if (nn <= 0) continue;            // uniform across block
        if (nn > 2048) nn = 2048;
        const unsigned* e1 = E1 + (size_t)cb * CAPC + begin;

        if (t < 32) hist[t] = 0;
        __syncthreads();
        for (int i = t; i < nn; i += 256)
            atomicAdd(&hist[(e1[i] >> 6) & 31], 1);
        __syncthreads();

        if (t < 32) gb[t] = atomicAdd(&ftail[cb * 32 + t], hist[t]);
        if (t == 0) {
            int run = 0;
            for (int k = 0; k < 32; ++k) { boff[k] = run; run += hist[k]; }
            boff[32] = run;
        }
        __syncthreads();
        if (t < 32) cur[t] = boff[t];
        __syncthreads();

        for (int i = t; i < nn; i += 256) {
            unsigned v = e1[i];
            int k = (v >> 6) & 31;
            int pos = atomicAdd(&cur[k], 1);
            stage[pos] = ((v >> 11) << 6) | (v & 63);   // (src<<6)|(dst&63)
        }
        __syncthreads();

        const int tot = boff[32];
        for (int i = t; i < tot; i += 256) {
            int lo = 0, hi = 32;
#pragma unroll
            for (int it = 0; it < 5; ++it) {
                int mid = (lo + hi) >> 1;
                bool c = (boff[mid] <= i);
                lo = c ? mid : lo;
                hi = c ? hi : mid;
            }
            int p = gb[lo] + (i - boff[lo]);
            int fb = cb * 32 + lo;
            if (p < FCAP) E2[(size_t)fb * FCAP + p] = stage[i];
        }
        __syncthreads();                  // before next unit reuses hist/stage
    }
}

// ---------------- GEMM: hs = bf16( rinv * (x W^T + b) ) via MFMA ----------------
// 128 rows/block, 4 waves, 32 rows/wave (2 row-frags x 8 col-frags of 16x16x32).
// Split-bf16 3-product: x = xh+xl, W = wh+wl; h ~= xh*wh + xl*wh + xh*wl.
// W staged in LDS as bf16 hi/lo, [o][k] layout, byte ^= ((o&7)<<4) swizzle.
// In-degrees: LDS hist (aliased into wh) from the block's 2 E2 buckets,
// consumed into 8 registers before W staging overwrites the space.
__device__ inline void cvt8(const float4 a, const float4 b, bf16x8& h, bf16x8& l) {
    bf16x8 H, L;
#define CV(i, f) { unsigned short hb = f2bf(f); H[i] = (short)hb;               \
                   L[i] = (short)f2bf((f) - __uint_as_float((unsigned)hb << 16)); }
    CV(0, a.x) CV(1, a.y) CV(2, a.z) CV(3, a.w)
    CV(4, b.x) CV(5, b.y) CV(6, b.z) CV(7, b.w)
#undef CV
    h = H; l = L;
}

#define MFMA(a, b, c) __builtin_amdgcn_mfma_f32_16x16x32_bf16((a), (b), (c), 0, 0, 0)

__global__ __launch_bounds__(256) void k_gemm(const float* __restrict__ x,
                                              const float* __restrict__ W,
                                              const float* __restrict__ b,
                                              const unsigned* __restrict__ E2,
                                              const int* __restrict__ ftail,
                                              unsigned short* __restrict__ hs) {
    __shared__ __align__(16) unsigned short wh[CH * CH];   // 32 KB bf16 hi
    __shared__ __align__(16) unsigned short wl[CH * CH];   // 32 KB bf16 lo
    const int t = threadIdx.x;
    const int lane = t & 63;
    const int l15  = lane & 15;
    const int lhi  = lane >> 4;         // 0..3

    // ---- in-degree hist for this block's 128 rows (dbin aliases wh) ----
    int* dbin = (int*)wh;
    if (t < 128) dbin[t] = 0;
    __syncthreads();
    {
        const int fb0 = blockIdx.x * 2;
        int n0 = ftail[fb0]; if (n0 > FCAP) n0 = FCAP;
        const unsigned* e0 = E2 + (size_t)fb0 * FCAP;
        for (int i = t; i < n0; i += 256) atomicAdd(&dbin[e0[i] & 63], 1);
        const int fb1 = fb0 + 1;
        if (fb1 < NFB) {
            int n1 = ftail[fb1]; if (n1 > FCAP) n1 = FCAP;
            const unsigned* e1p = E2 + (size_t)fb1 * FCAP;
            for (int i = t; i < n1; i += 256) atomicAdd(&dbin[64 + (e1p[i] & 63)], 1);
        }
    }
    __syncthreads();
    float rreg[2][4];                   // rinv for this thread's 8 output rows
#pragma unroll
    for (int rf = 0; rf < 2; ++rf) {
        int lb = (t >> 6) * 32 + rf * 16 + lhi * 4;
#pragma unroll
        for (int j = 0; j < 4; ++j)
            rreg[rf][j] = rsqrtf((float)(dbin[lb + j] + 1));
    }
    __syncthreads();

    // ---- stage W -> LDS bf16 hi/lo, swizzled (overwrites dbin space) ----
    for (int c = t; c < 2048; c += 256) {                  // 128 rows x 16 chunks
        int o   = c >> 4;
        int kk  = (c & 15) << 3;                           // k chunk start
        const float* wp = &W[(size_t)o * CH + kk];
        float4 w0 = *(const float4*)wp;
        float4 w1 = *(const float4*)(wp + 4);
        bf16x8 H, L;
        cvt8(w0, w1, H, L);
        unsigned boff = ((unsigned)((o << 8) | (kk << 1))) ^ ((unsigned)(o & 7) << 4);
        *(bf16x8*)((char*)wh + boff) = H;
        *(bf16x8*)((char*)wl + boff) = L;
    }
    __syncthreads();

    const int kc = lhi << 3;            // k-chunk base within a 32-wide k-step
    const int row_base = blockIdx.x * 128 + (t >> 6) * 32;

    int r0 = row_base + l15;       if (r0 > N_NODES - 1) r0 = N_NODES - 1;
    int r1 = row_base + 16 + l15;  if (r1 > N_NODES - 1) r1 = N_NODES - 1;
    const float* x0 = &x[(size_t)r0 * CH + kc];
    const float* x1 = &x[(size_t)r1 * CH + kc];

    // issue the wave's entire x read as one burst (latency hidden once)
    float4 xa[4][2], xb[4][2];
#pragma unroll
    for (int ks = 0; ks < 4; ++ks) {
        xa[ks][0] = *(const float4*)(x0 + ks * 32);
        xa[ks][1] = *(const float4*)(x0 + ks * 32 + 4);
        xb[ks][0] = *(const float4*)(x1 + ks * 32);
        xb[ks][1] = *(const float4*)(x1 + ks * 32 + 4);
    }

    f32x4 acc[2][8];
#pragma unroll
    for (int rf = 0; rf < 2; ++rf)
#pragma unroll
        for (int cf = 0; cf < 8; ++cf)
            acc[rf][cf] = (f32x4){0.f, 0.f, 0.f, 0.f};

#pragma unroll
    for (int ks = 0; ks < 4; ++ks) {
        bf16x8 ah0, al0, ah1, al1;
        cvt8(xa[ks][0], xa[ks][1], ah0, al0);
        cvt8(xb[ks][0], xb[ks][1], ah1, al1);
        const unsigned kb = (unsigned)((ks * 32 + kc) << 1);
#pragma unroll
        for (int cf = 0; cf < 8; ++cf) {
            int o = cf * 16 + l15;
            unsigned boff = (((unsigned)(o << 8)) + kb) ^ ((unsigned)(o & 7) << 4);
            bf16x8 bh = *(const bf16x8*)((const char*)wh + boff);
            bf16x8 bl = *(const bf16x8*)((const char*)wl + boff);
            acc[0][cf] = MFMA(ah0, bh, acc[0][cf]);
            acc[1][cf] = MFMA(ah1, bh, acc[1][cf]);
            acc[0][cf] = MFMA(al0, bh, acc[0][cf]);
            acc[1][cf] = MFMA(al1, bh, acc[1][cf]);
            acc[0][cf] = MFMA(ah0, bl, acc[0][cf]);
            acc[1][cf] = MFMA(ah1, bl, acc[1][cf]);
        }
    }

    // ---- epilogue: D[row=(lane>>4)*4+j][col=lane&15] per 16x16 tile ----
    float bcol[8];
#pragma unroll
    for (int cf = 0; cf < 8; ++cf) bcol[cf] = b[cf * 16 + l15];

#pragma unroll
    for (int rf = 0; rf < 2; ++rf) {
        int rb = row_base + rf * 16 + lhi * 4;             // multiple of 4
        if (rb >= N_NODES) continue;                       // N_NODES % 4 == 0
#pragma unroll
        for (int j = 0; j < 4; ++j) {
            size_t ro = (size_t)(rb + j) * CH;
            float ri = rreg[rf][j];
#pragma unroll
            for (int cf = 0; cf < 8; ++cf)
                hs[ro + cf * 16 + l15] = f2bf(ri * (acc[rf][cf][j] + bcol[cf]));
        }
    }
}

// ---------------- fine-bucket SpMM: LDS sort + uint4 gather ----------------
#define ACC8(u)                                                            \
    do {                                                                   \
        acc[0] += bflo((u).x); acc[1] += bfhi((u).x);                      \
        acc[2] += bflo((u).y); acc[3] += bfhi((u).y);                      \
        acc[4] += bflo((u).z); acc[5] += bfhi((u).z);                      \
        acc[6] += bflo((u).w); acc[7] += bfhi((u).w);                      \
    } while (0)

__global__ __launch_bounds__(256) void k_spmm(const unsigned* __restrict__ E2,
                                              const int* __restrict__ ftail,
                                              const unsigned short* __restrict__ hs,
                                              float* __restrict__ out) {
    __shared__ int bins[64];
    __shared__ int boff[65];
    __shared__ int cur[64];
    __shared__ int srt[FCAP];
    const int fb    = blockIdx.x;
    const int node0 = fb * 64;
    const int t     = threadIdx.x;
    const unsigned* e2 = E2 + (size_t)fb * FCAP;
    const uint4* hp = (const uint4*)hs;        // row s at hp[s*16 + lane]

    if (t < 64) bins[t] = 0;
    int n = ftail[fb]; if (n > FCAP) n = FCAP;
    __syncthreads();

    for (int i = t; i < n; i += 256) atomicAdd(&bins[e2[i] & 63], 1);
    __syncthreads();

    if (t == 0) {
        int run = 0;
        for (int k = 0; k < 64; ++k) { boff[k] = run; run += bins[k]; }
        boff[64] = run;
    }
    __syncthreads();
    if (t < 64) cur[t] = boff[t];
    __syncthreads();

    for (int i = t; i < n; i += 256) {
        unsigned v = e2[i];
        int pos = atomicAdd(&cur[v & 63], 1);
        srt[pos] = (int)(v >> 6);
    }
    __syncthreads();

    // gather: 16 groups x 16 lanes; group g handles nodes 4g..4g+3
    const int grp  = t >> 4;
    const int lane = t & 15;
#pragma unroll
    for (int r = 0; r < 4; ++r) {
        const int nl   = grp * 4 + r;
        const int node = node0 + nl;
        if (node >= N_NODES) continue;
        float acc[8] = {};
        {   // self term
            uint4 u = hp[(size_t)node * 16 + lane];
            ACC8(u);
        }
        int e  = boff[nl];
        int e1 = boff[nl + 1];
        for (; e + 8 <= e1; e += 8) {          // 8-deep: 128B/lane in flight
            int s0 = srt[e + 0], s1 = srt[e + 1], s2 = srt[e + 2], s3 = srt[e + 3];
            int s4 = srt[e + 4], s5 = srt[e + 5], s6 = srt[e + 6], s7 = srt[e + 7];
            uint4 u0 = hp[(size_t)s0 * 16 + lane];
            uint4 u1 = hp[(size_t)s1 * 16 + lane];
            uint4 u2 = hp[(size_t)s2 * 16 + lane];
            uint4 u3 = hp[(size_t)s3 * 16 + lane];
            uint4 u4 = hp[(size_t)s4 * 16 + lane];
            uint4 u5 = hp[(size_t)s5 * 16 + lane];
            uint4 u6 = hp[(size_t)s6 * 16 + lane];
            uint4 u7 = hp[(size_t)s7 * 16 + lane];
            ACC8(u0); ACC8(u1); ACC8(u2); ACC8(u3);
            ACC8(u4); ACC8(u5); ACC8(u6); ACC8(u7);
        }
        for (; e + 4 <= e1; e += 4) {
            int s0 = srt[e + 0];
            int s1 = srt[e + 1];
            int s2 = srt[e + 2];
            int s3 = srt[e + 3];
            uint4 u0 = hp[(size_t)s0 * 16 + lane];
            uint4 u1 = hp[(size_t)s1 * 16 + lane];
            uint4 u2 = hp[(size_t)s2 * 16 + lane];
            uint4 u3 = hp[(size_t)s3 * 16 + lane];
            ACC8(u0); ACC8(u1); ACC8(u2); ACC8(u3);
        }
        for (; e < e1; ++e) {
            uint4 u = hp[(size_t)srt[e] * 16 + lane];
            ACC8(u);
        }
        float ri = rsqrtf((float)(bins[nl] + 1));   // local rinv (== old k_deg)
        f32x4 o0, o1;
        o0[0] = ri * acc[0]; o0[1] = ri * acc[1]; o0[2] = ri * acc[2]; o0[3] = ri * acc[3];
        o1[0] = ri * acc[4]; o1[1] = ri * acc[5]; o1[2] = ri * acc[6]; o1[3] = ri * acc[7];
        *(f32x4*)&out[(size_t)node * CH + lane * 8]     = o0;
        *(f32x4*)&out[(size_t)node * CH + lane * 8 + 4] = o1;
    }
}

extern "C" void kernel_launch(void* const* d_in, const int* in_sizes, int n_in,
                              void* d_out, int out_size, void* d_ws, size_t ws_size,
                              hipStream_t stream) {
    const float* x  = (const float*)d_in[0];
    const int*   ei = (const int*)d_in[1];
    const float* W  = (const float*)d_in[2];
    const float* b  = (const float*)d_in[3];
    float* out = (float*)d_out;

    const int* src = (const int*)ei;
    const int* dst = (const int*)ei + N_EDGES;

    // workspace layout (4-byte units; all region starts 16B-aligned):
    //   ctail : 64     (49 used)
    //   ftail : 1600   (1568 used)
    //   histG : 49*782 = 38318, rounded 38336
    //   E1    : 49*34816   = 1,705,984
    //   E2    : 1563*1280  = 2,000,640
    //   hs    : N*CH bf16  = 12,800,000 shorts
    int*      ctail = (int*)d_ws;
    int*      ftail = ctail + 64;
    int*      histG = ftail + 1600;
    unsigned* E1    = (unsigned*)(histG + 38336);
    unsigned* E2    = E1 + (size_t)NC * CAPC;
    unsigned short* hs = (unsigned short*)(E2 + (size_t)NFB * FCAP);

    void* args[] = {(void*)&src, (void*)&dst, (void*)&ctail, (void*)&ftail,
                    (void*)&histG, (void*)&E1, (void*)&E2};
    (void)hipLaunchCooperativeKernel((void*)k_sort, dim3(NBLKA), dim3(256),
                                     args, 0, stream);
    k_gemm<<<NBLKA, 256, 0, stream>>>(x, W, b, E2, ftail, hs);
    k_spmm<<<NFB, 256, 0, stream>>>(E2, ftail, hs, out);
}

// Round 7
// 221.940 us; speedup vs baseline: 3.4374x; 3.4374x over previous
//
#include <hip/hip_runtime.h>
#include <hip/hip_bf16.h>

// GCN layer: out = D^-1/2 (A + I) D^-1/2 (x W^T + b)
// R12: R10's proven 4-kernel sort chain (separate dispatches — R11 showed
//      cooperative grid.sync costs ~170us EACH on MI355X: device-scope
//      fence across 8 non-coherent XCD L2s; never grid-sync here) +
//      validated consolidation: memset folded into k_histA, k_deg deleted
//      (gemm derives degrees from its 2 E2 buckets; spmm computes rinv
//      locally from bins). 6 dispatches total.
//   1. k_histA: per 2048-edge block: 49-bin LDS hist -> histG[k][blk]; zeros ftail
//   2. k_scanA: per bucket k: exclusive scan over 782 block hists
//   3. k_place: LDS counting sort; writeout at histG offsets (no atomics)
//   4. k_sortB: per (coarse,chunk): re-bin into 64-node fine buckets
//   5. k_gemm:  hs = bf16( rinv[r] * (x W^T + b) ) via mfma_f32_16x16x32_bf16;
//               in-degrees from E2 buckets (LDS hist aliased into wh)
//   6. k_spmm:  per fine bucket: LDS counting sort -> exact per-node runs,
//               16-lane uint4 gather 8-deep; rinv local from bins.

#define N_NODES 100000
#define N_EDGES 1600000
#define CH 128
#define NC 49            // coarse buckets of 2048 nodes
#define NBLKA 782        // sort blocks (2048 edges each)
#define CAPC 34816       // 17*2048; mean 32768 + 11 sigma
#define NCHUNK 17
#define NFB 1563         // fine buckets of 64 nodes (1563*64 = 100032)
#define FCAP 1280        // mean 1024 + 8 sigma

using bf16x8 = __attribute__((ext_vector_type(8))) short;   // 8 bf16 in 4 VGPRs
using f32x4  = __attribute__((ext_vector_type(4))) float;   // MFMA acc

__device__ inline unsigned short f2bf(float f) {          // RNE float->bf16
    unsigned u = __float_as_uint(f);
    u += 0x7fffu + ((u >> 16) & 1u);
    return (unsigned short)(u >> 16);
}
__device__ inline float bflo(unsigned u) { return __uint_as_float(u << 16); }
__device__ inline float bfhi(unsigned u) { return __uint_as_float(u & 0xffff0000u); }

// ---------------- phase A1: per-block 49-bin histogram (+ ftail zero) ------------
__global__ __launch_bounds__(256) void k_histA(const int* __restrict__ dst,
                                               int* __restrict__ histG,
                                               int* __restrict__ ftail) {
    __shared__ int hist[NC];
    const int t    = threadIdx.x;
    const int base = blockIdx.x * 2048;
    const int n    = min(2048, N_EDGES - base);   // 2048, or 512 in last block
    { int i = blockIdx.x * 256 + t; if (i < 1600) ftail[i] = 0; }
    if (t < NC) hist[t] = 0;
    __syncthreads();
#pragma unroll
    for (int h = 0; h < 2; ++h) {
        int idx = h * 1024 + 4 * t;
        if (idx < n) {
            int4 dv = *(const int4*)&dst[base + idx];
            atomicAdd(&hist[dv.x >> 11], 1);
            atomicAdd(&hist[dv.y >> 11], 1);
            atomicAdd(&hist[dv.z >> 11], 1);
            atomicAdd(&hist[dv.w >> 11], 1);
        }
    }
    __syncthreads();
    if (t < NC) histG[(size_t)t * NBLKA + blockIdx.x] = hist[t];
}

// ---------------- phase A2: exclusive scan per bucket (exact offsets) ------------
__global__ __launch_bounds__(256) void k_scanA(int* __restrict__ histG,
                                               int* __restrict__ ctail) {
    __shared__ int part[256];
    const int k = blockIdx.x;                    // 0..NC-1
    int* h = histG + (size_t)k * NBLKA;
    const int t = threadIdx.x;
    const int base = t * 4;                      // 256*4 >= 782
    int a0 = 0, a1 = 0, a2 = 0, a3 = 0;
    if (base + 0 < NBLKA) a0 = h[base + 0];
    if (base + 1 < NBLKA) a1 = h[base + 1];
    if (base + 2 < NBLKA) a2 = h[base + 2];
    if (base + 3 < NBLKA) a3 = h[base + 3];
    const int s = a0 + a1 + a2 + a3;
    part[t] = s;
    __syncthreads();
    for (int off = 1; off < 256; off <<= 1) {    // Hillis-Steele inclusive scan
        int x = (t >= off) ? part[t - off] : 0;
        __syncthreads();
        part[t] += x;
        __syncthreads();
    }
    int r = part[t] - s;                         // exclusive prefix of chunk
    if (t == 255) ctail[k] = part[255];
    if (base + 0 < NBLKA) { h[base + 0] = r; r += a0; }
    if (base + 1 < NBLKA) { h[base + 1] = r; r += a1; }
    if (base + 2 < NBLKA) { h[base + 2] = r; r += a2; }
    if (base + 3 < NBLKA) { h[base + 3] = r; r += a3; }
}

// ---------------- phase A3: LDS counting sort, writeout at exact offsets ---------
__global__ __launch_bounds__(256) void k_place(const int* __restrict__ src,
                                               const int* __restrict__ dst,
                                               const int* __restrict__ histG,
                                               unsigned* __restrict__ E1) {
    __shared__ int hist[NC];
    __shared__ int boff[NC + 1];
    __shared__ int cur[NC];
    __shared__ int gb[NC];
    __shared__ unsigned stage[2048];
    const int t    = threadIdx.x;
    const int base = blockIdx.x * 2048;
    const int n    = min(2048, N_EDGES - base);

    if (t < NC) {
        hist[t] = 0;
        gb[t] = histG[(size_t)t * NBLKA + blockIdx.x];   // exact, no atomics
    }
    __syncthreads();

    int s[8], d[8];
#pragma unroll
    for (int h = 0; h < 2; ++h) {
        int idx = h * 1024 + 4 * t;
        if (idx < n) {                    // n in {512,2048}: int4 never straddles
            int4 sv = *(const int4*)&src[base + idx];
            int4 dv = *(const int4*)&dst[base + idx];
            s[4*h+0] = sv.x; s[4*h+1] = sv.y; s[4*h+2] = sv.z; s[4*h+3] = sv.w;
            d[4*h+0] = dv.x; d[4*h+1] = dv.y; d[4*h+2] = dv.z; d[4*h+3] = dv.w;
        } else {
            d[4*h+0] = d[4*h+1] = d[4*h+2] = d[4*h+3] = -1;
            s[4*h+0] = s[4*h+1] = s[4*h+2] = s[4*h+3] = 0;
        }
    }
#pragma unroll
    for (int j = 0; j < 8; ++j)
        if (d[j] >= 0) atomicAdd(&hist[d[j] >> 11], 1);
    __syncthreads();

    if (t == 0) {
        int run = 0;
        for (int k = 0; k < NC; ++k) { boff[k] = run; run += hist[k]; }
        boff[NC] = run;
    }
    __syncthreads();
    if (t < NC) cur[t] = boff[t];
    __syncthreads();

#pragma unroll
    for (int j = 0; j < 8; ++j)
        if (d[j] >= 0) {
            int k = d[j] >> 11;
            int pos = atomicAdd(&cur[k], 1);
            stage[pos] = ((unsigned)s[j] << 11) | (unsigned)(d[j] & 2047);
        }
    __syncthreads();

    const int tot = boff[NC];
    for (int i = t; i < tot; i += 256) {
        int lo = 0, hi = NC;              // invariant: boff[lo] <= i < boff[hi]
#pragma unroll
        for (int it = 0; it < 6; ++it) {
            int mid = (lo + hi) >> 1;
            bool c = (boff[mid] <= i);
            lo = c ? mid : lo;
            hi = c ? hi : mid;
        }
        int p = gb[lo] + (i - boff[lo]);
        if (p < CAPC) E1[(size_t)lo * CAPC + p] = stage[i];
    }
}

// ---------------- phase B: re-bin coarse -> 64-node fine buckets ----------------
__global__ __launch_bounds__(256) void k_sortB(const unsigned* __restrict__ E1,
                                               const int* __restrict__ ctail,
                                               int* __restrict__ ftail,
                                               unsigned* __restrict__ E2) {
    __shared__ int hist[32];
    __shared__ int boff[33];
    __shared__ int cur[32];
    __shared__ int gb[32];
    __shared__ unsigned stage[2048];
    const int cb = blockIdx.x / NCHUNK;
    const int ch = blockIdx.x % NCHUNK;
    const int t  = threadIdx.x;
    int cnt = ctail[cb]; if (cnt > CAPC) cnt = CAPC;
    const int begin = ch * 2048;
    int n = cnt - begin;
    if (n <= 0) return;                   // uniform across block
    if (n > 2048) n = 2048;
    const unsigned* e1 = E1 + (size_t)cb * CAPC + begin;

    if (t < 32) hist[t] = 0;
    __syncthreads();

    for (int i = t; i < n; i += 256)
        atomicAdd(&hist[(e1[i] >> 6) & 31], 1);
    __syncthreads();

    if (t < 32) gb[t] = atomicAdd(&ftail[cb * 32 + t], hist[t]);
    if (t == 0) {
        int run = 0;
        for (int k = 0; k < 32; ++k) { boff[k] = run; run += hist[k]; }
        boff[32] = run;
    }
    __syncthreads();
    if (t < 32) cur[t] = boff[t];
    __syncthreads();

    for (int i = t; i < n; i += 256) {
        unsigned v = e1[i];
        int k = (v >> 6) & 31;
        int pos = atomicAdd(&cur[k], 1);
        stage[pos] = ((v >> 11) << 6) | (v & 63);   // (src<<6)|(dst&63)
    }
    __syncthreads();

    const int tot = boff[32];
    for (int i = t; i < tot; i += 256) {
        int lo = 0, hi = 32;
#pragma unroll
        for (int it = 0; it < 5; ++it) {
            int mid = (lo + hi) >> 1;
            bool c = (boff[mid] <= i);
            lo = c ? mid : lo;
            hi = c ? hi : mid;
        }
        int p = gb[lo] + (i - boff[lo]);
        int fb = cb * 32 + lo;
        if (p < FCAP) E2[(size_t)fb * FCAP + p] = stage[i];
    }
}

// ---------------- GEMM: hs = bf16( rinv * (x W^T + b) ) via MFMA ----------------
// 128 rows/block, 4 waves, 32 rows/wave (2 row-frags x 8 col-frags of 16x16x32).
// Split-bf16 3-product: x = xh+xl, W = wh+wl; h ~= xh*wh + xl*wh + xh*wl.
// W staged in LDS as bf16 hi/lo, [o][k] layout, byte ^= ((o&7)<<4) swizzle.
// In-degrees: LDS hist (aliased into wh) from the block's 2 E2 buckets,
// consumed into 8 registers before W staging overwrites the space.
__device__ inline void cvt8(const float4 a, const float4 b, bf16x8& h, bf16x8& l) {
    bf16x8 H, L;
#define CV(i, f) { unsigned short hb = f2bf(f); H[i] = (short)hb;               \
                   L[i] = (short)f2bf((f) - __uint_as_float((unsigned)hb << 16)); }
    CV(0, a.x) CV(1, a.y) CV(2, a.z) CV(3, a.w)
    CV(4, b.x) CV(5, b.y) CV(6, b.z) CV(7, b.w)
#undef CV
    h = H; l = L;
}

#define MFMA(a, b, c) __builtin_amdgcn_mfma_f32_16x16x32_bf16((a), (b), (c), 0, 0, 0)

__global__ __launch_bounds__(256) void k_gemm(const float* __restrict__ x,
                                              const float* __restrict__ W,
                                              const float* __restrict__ b,
                                              const unsigned* __restrict__ E2,
                                              const int* __restrict__ ftail,
                                              unsigned short* __restrict__ hs) {
    __shared__ __align__(16) unsigned short wh[CH * CH];   // 32 KB bf16 hi
    __shared__ __align__(16) unsigned short wl[CH * CH];   // 32 KB bf16 lo
    const int t = threadIdx.x;
    const int lane = t & 63;
    const int l15  = lane & 15;
    const int lhi  = lane >> 4;         // 0..3

    // ---- in-degree hist for this block's 128 rows (dbin aliases wh) ----
    int* dbin = (int*)wh;
    if (t < 128) dbin[t] = 0;
    __syncthreads();
    {
        const int fb0 = blockIdx.x * 2;
        int n0 = ftail[fb0]; if (n0 > FCAP) n0 = FCAP;
        const unsigned* e0 = E2 + (size_t)fb0 * FCAP;
        for (int i = t; i < n0; i += 256) atomicAdd(&dbin[e0[i] & 63], 1);
        const int fb1 = fb0 + 1;
        if (fb1 < NFB) {
            int n1 = ftail[fb1]; if (n1 > FCAP) n1 = FCAP;
            const unsigned* e1p = E2 + (size_t)fb1 * FCAP;
            for (int i = t; i < n1; i += 256) atomicAdd(&dbin[64 + (e1p[i] & 63)], 1);
        }
    }
    __syncthreads();
    float rreg[2][4];                   // rinv for this thread's 8 output rows
#pragma unroll
    for (int rf = 0; rf < 2; ++rf) {
        int lb = (t >> 6) * 32 + rf * 16 + lhi * 4;
#pragma unroll
        for (int j = 0; j < 4; ++j)
            rreg[rf][j] = rsqrtf((float)(dbin[lb + j] + 1));
    }
    __syncthreads();

    // ---- stage W -> LDS bf16 hi/lo, swizzled (overwrites dbin space) ----
    for (int c = t; c < 2048; c += 256) {                  // 128 rows x 16 chunks
        int o   = c >> 4;
        int kk  = (c & 15) << 3;                           // k chunk start
        const float* wp = &W[(size_t)o * CH + kk];
        float4 w0 = *(const float4*)wp;
        float4 w1 = *(const float4*)(wp + 4);
        bf16x8 H, L;
        cvt8(w0, w1, H, L);
        unsigned boff = ((unsigned)((o << 8) | (kk << 1))) ^ ((unsigned)(o & 7) << 4);
        *(bf16x8*)((char*)wh + boff) = H;
        *(bf16x8*)((char*)wl + boff) = L;
    }
    __syncthreads();

    const int kc = lhi << 3;            // k-chunk base within a 32-wide k-step
    const int row_base = blockIdx.x * 128 + (t >> 6) * 32;

    int r0 = row_base + l15;       if (r0 > N_NODES - 1) r0 = N_NODES - 1;
    int r1 = row_base + 16 + l15;  if (r1 > N_NODES - 1) r1 = N_NODES - 1;
    const float* x0 = &x[(size_t)r0 * CH + kc];
    const float* x1 = &x[(size_t)r1 * CH + kc];

    // issue the wave's entire x read as one burst (latency hidden once)
    float4 xa[4][2], xb[4][2];
#pragma unroll
    for (int ks = 0; ks < 4; ++ks) {
        xa[ks][0] = *(const float4*)(x0 + ks * 32);
        xa[ks][1] = *(const float4*)(x0 + ks * 32 + 4);
        xb[ks][0] = *(const float4*)(x1 + ks * 32);
        xb[ks][1] = *(const float4*)(x1 + ks * 32 + 4);
    }

    f32x4 acc[2][8];
#pragma unroll
    for (int rf = 0; rf < 2; ++rf)
#pragma unroll
        for (int cf = 0; cf < 8; ++cf)
            acc[rf][cf] = (f32x4){0.f, 0.f, 0.f, 0.f};

#pragma unroll
    for (int ks = 0; ks < 4; ++ks) {
        bf16x8 ah0, al0, ah1, al1;
        cvt8(xa[ks][0], xa[ks][1], ah0, al0);
        cvt8(xb[ks][0], xb[ks][1], ah1, al1);
        const unsigned kb = (unsigned)((ks * 32 + kc) << 1);
#pragma unroll
        for (int cf = 0; cf < 8; ++cf) {
            int o = cf * 16 + l15;
            unsigned boff = (((unsigned)(o << 8)) + kb) ^ ((unsigned)(o & 7) << 4);
            bf16x8 bh = *(const bf16x8*)((const char*)wh + boff);
            bf16x8 bl = *(const bf16x8*)((const char*)wl + boff);
            acc[0][cf] = MFMA(ah0, bh, acc[0][cf]);
            acc[1][cf] = MFMA(ah1, bh, acc[1][cf]);
            acc[0][cf] = MFMA(al0, bh, acc[0][cf]);
            acc[1][cf] = MFMA(al1, bh, acc[1][cf]);
            acc[0][cf] = MFMA(ah0, bl, acc[0][cf]);
            acc[1][cf] = MFMA(ah1, bl, acc[1][cf]);
        }
    }

    // ---- epilogue: D[row=(lane>>4)*4+j][col=lane&15] per 16x16 tile ----
    float bcol[8];
#pragma unroll
    for (int cf = 0; cf < 8; ++cf) bcol[cf] = b[cf * 16 + l15];

#pragma unroll
    for (int rf = 0; rf < 2; ++rf) {
        int rb = row_base + rf * 16 + lhi * 4;             // multiple of 4
        if (rb >= N_NODES) continue;                       // N_NODES % 4 == 0
#pragma unroll
        for (int j = 0; j < 4; ++j) {
            size_t ro = (size_t)(rb + j) * CH;
            float ri = rreg[rf][j];
#pragma unroll
            for (int cf = 0; cf < 8; ++cf)
                hs[ro + cf * 16 + l15] = f2bf(ri * (acc[rf][cf][j] + bcol[cf]));
        }
    }
}

// ---------------- fine-bucket SpMM: LDS sort + uint4 gather ----------------
#define ACC8(u)                                                            \
    do {                                                                   \
        acc[0] += bflo((u).x); acc[1] += bfhi((u).x);                      \
        acc[2] += bflo((u).y); acc[3] += bfhi((u).y);                      \
        acc[4] += bflo((u).z); acc[5] += bfhi((u).z);                      \
        acc[6] += bflo((u).w); acc[7] += bfhi((u).w);                      \
    } while (0)

__global__ __launch_bounds__(256) void k_spmm(const unsigned* __restrict__ E2,
                                              const int* __restrict__ ftail,
                                              const unsigned short* __restrict__ hs,
                                              float* __restrict__ out) {
    __shared__ int bins[64];
    __shared__ int boff[65];
    __shared__ int cur[64];
    __shared__ int srt[FCAP];
    const int fb    = blockIdx.x;
    const int node0 = fb * 64;
    const int t     = threadIdx.x;
    const unsigned* e2 = E2 + (size_t)fb * FCAP;
    const uint4* hp = (const uint4*)hs;        // row s at hp[s*16 + lane]

    if (t < 64) bins[t] = 0;
    int n = ftail[fb]; if (n > FCAP) n = FCAP;
    __syncthreads();

    for (int i = t; i < n; i += 256) atomicAdd(&bins[e2[i] & 63], 1);
    __syncthreads();

    if (t == 0) {
        int run = 0;
        for (int k = 0; k < 64; ++k) { boff[k] = run; run += bins[k]; }
        boff[64] = run;
    }
    __syncthreads();
    if (t < 64) cur[t] = boff[t];
    __syncthreads();

    for (int i = t; i < n; i += 256) {
        unsigned v = e2[i];
        int pos = atomicAdd(&cur[v & 63], 1);
        srt[pos] = (int)(v >> 6);
    }
    __syncthreads();

    // gather: 16 groups x 16 lanes; group g handles nodes 4g..4g+3
    const int grp  = t >> 4;
    const int lane = t & 15;
#pragma unroll
    for (int r = 0; r < 4; ++r) {
        const int nl   = grp * 4 + r;
        const int node = node0 + nl;
        if (node >= N_NODES) continue;
        float acc[8] = {};
        {   // self term
            uint4 u = hp[(size_t)node * 16 + lane];
            ACC8(u);
        }
        int e  = boff[nl];
        int e1 = boff[nl + 1];
        for (; e + 8 <= e1; e += 8) {          // 8-deep: 128B/lane in flight
            int s0 = srt[e + 0], s1 = srt[e + 1], s2 = srt[e + 2], s3 = srt[e + 3];
            int s4 = srt[e + 4], s5 = srt[e + 5], s6 = srt[e + 6], s7 = srt[e + 7];
            uint4 u0 = hp[(size_t)s0 * 16 + lane];
            uint4 u1 = hp[(size_t)s1 * 16 + lane];
            uint4 u2 = hp[(size_t)s2 * 16 + lane];
            uint4 u3 = hp[(size_t)s3 * 16 + lane];
            uint4 u4 = hp[(size_t)s4 * 16 + lane];
            uint4 u5 = hp[(size_t)s5 * 16 + lane];
            uint4 u6 = hp[(size_t)s6 * 16 + lane];
            uint4 u7 = hp[(size_t)s7 * 16 + lane];
            ACC8(u0); ACC8(u1); ACC8(u2); ACC8(u3);
            ACC8(u4); ACC8(u5); ACC8(u6); ACC8(u7);
        }
        for (; e + 4 <= e1; e += 4) {
            int s0 = srt[e + 0];
            int s1 = srt[e + 1];
            int s2 = srt[e + 2];
            int s3 = srt[e + 3];
            uint4 u0 = hp[(size_t)s0 * 16 + lane];
            uint4 u1 = hp[(size_t)s1 * 16 + lane];
            uint4 u2 = hp[(size_t)s2 * 16 + lane];
            uint4 u3 = hp[(size_t)s3 * 16 + lane];
            ACC8(u0); ACC8(u1); ACC8(u2); ACC8(u3);
        }
        for (; e < e1; ++e) {
            uint4 u = hp[(size_t)srt[e] * 16 + lane];
            ACC8(u);
        }
        float ri = rsqrtf((float)(bins[nl] + 1));   // local rinv (== old k_deg)
        f32x4 o0, o1;
        o0[0] = ri * acc[0]; o0[1] = ri * acc[1]; o0[2] = ri * acc[2]; o0[3] = ri * acc[3];
        o1[0] = ri * acc[4]; o1[1] = ri * acc[5]; o1[2] = ri * acc[6]; o1[3] = ri * acc[7];
        *(f32x4*)&out[(size_t)node * CH + lane * 8]     = o0;
        *(f32x4*)&out[(size_t)node * CH + lane * 8 + 4] = o1;
    }
}

extern "C" void kernel_launch(void* const* d_in, const int* in_sizes, int n_in,
                              void* d_out, int out_size, void* d_ws, size_t ws_size,
                              hipStream_t stream) {
    const float* x  = (const float*)d_in[0];
    const int*   ei = (const int*)d_in[1];
    const float* W  = (const float*)d_in[2];
    const float* b  = (const float*)d_in[3];
    float* out = (float*)d_out;

    const int* src = (const int*)ei;
    const int* dst = (const int*)ei + N_EDGES;

    // workspace layout (4-byte units; all region starts 16B-aligned):
    //   ctail : 64     (49 used)
    //   ftail : 1600   (1568 used)
    //   histG : 49*782 = 38318, rounded 38336
    //   E1    : 49*34816   = 1,705,984
    //   E2    : 1563*1280  = 2,000,640
    //   hs    : N*CH bf16  = 12,800,000 shorts
    int*      ctail = (int*)d_ws;
    int*      ftail = ctail + 64;
    int*      histG = ftail + 1600;
    unsigned* E1    = (unsigned*)(histG + 38336);
    unsigned* E2    = E1 + (size_t)NC * CAPC;
    unsigned short* hs = (unsigned short*)(E2 + (size_t)NFB * FCAP);

    k_histA<<<NBLKA, 256, 0, stream>>>(dst, histG, ftail);
    k_scanA<<<NC, 256, 0, stream>>>(histG, ctail);
    k_place<<<NBLKA, 256, 0, stream>>>(src, dst, histG, E1);
    k_sortB<<<NC * NCHUNK, 256, 0, stream>>>(E1, ctail, ftail, E2);
    k_gemm<<<NBLKA, 256, 0, stream>>>(x, W, b, E2, ftail, hs);
    k_spmm<<<NFB, 256, 0, stream>>>(E2, ftail, hs, out);
}